// Round 1
// baseline (228.794 us; speedup 1.0000x reference)
//
#include <hip/hip_runtime.h>

#define B_ 16
#define S_ 8192
#define D_ 128
#define C_ 64

constexpr int THREADS = 512;
constexpr int ROWS_PB = 512;   // rows per block
constexpr int TR      = 8;     // rows per thread (512 threads = 64 rowthreads x 8 tc)

// ws float layout:
//   [0, 8192)        cnT[d][c]  (normalized centroids, transposed)
//   [8192, 139264)   ksum  [B][C][D]
//   [139264, 270336) vsum  [B][C][D]
//   [270336, 271360) counts [B][C]
#define WS_CNT_OFF   0
#define WS_KSUM_OFF  8192
#define WS_VSUM_OFF  (8192 + B_*C_*D_)
#define WS_CNTS_OFF  (8192 + 2*B_*C_*D_)

__global__ void normalize_centroids_k(const float* __restrict__ cen,
                                      float* __restrict__ cnT) {
    int tid = threadIdx.x;          // 512 threads, 1 block
    int c = tid >> 3;               // 0..63
    int l = tid & 7;                // 8 lanes per centroid
    float4 v[4];
    float s = 0.f;
#pragma unroll
    for (int q = 0; q < 4; ++q) {
        v[q] = *(const float4*)&cen[c * D_ + l * 16 + q * 4];
        s += v[q].x * v[q].x + v[q].y * v[q].y + v[q].z * v[q].z + v[q].w * v[q].w;
    }
#pragma unroll
    for (int m = 1; m < 8; m <<= 1) s += __shfl_xor(s, m, 8);
    float n = fmaxf(sqrtf(s), 1e-12f);
#pragma unroll
    for (int q = 0; q < 4; ++q) {
        int d = l * 16 + q * 4;
        cnT[(d + 0) * C_ + c] = v[q].x / n;
        cnT[(d + 1) * C_ + c] = v[q].y / n;
        cnT[(d + 2) * C_ + c] = v[q].z / n;
        cnT[(d + 3) * C_ + c] = v[q].w / n;
    }
}

__global__ __launch_bounds__(THREADS, 2) void assign_accum_k(
    const float* __restrict__ keys, const float* __restrict__ values,
    const float* __restrict__ mask, const float* __restrict__ cnT_g,
    float* __restrict__ g_ksum, float* __restrict__ g_vsum,
    float* __restrict__ g_cnt, float* __restrict__ out_asg) {

    __shared__ float cnT[D_ * C_];    // 32 KB
    __shared__ float accK[C_ * D_];   // 32 KB
    __shared__ float accV[C_ * D_];   // 32 KB
    __shared__ float cntL[C_];
    __shared__ short asgL[ROWS_PB];

    const int tid = threadIdx.x;
    const int bid = blockIdx.x;
    const int batch = bid >> 4;           // 16 blocks per batch
    const int srow0 = (bid & 15) * ROWS_PB;

    for (int i = tid; i < D_ * C_; i += THREADS) {
        cnT[i] = cnT_g[i];
        accK[i] = 0.f;
        accV[i] = 0.f;
    }
    if (tid < C_) cntL[tid] = 0.f;
    __syncthreads();

    const int tc  = tid & 7;      // cluster group: clusters tc*8 .. tc*8+7
    const int trt = tid >> 3;     // 0..63, owns 8 consecutive rows
    const int row0 = srow0 + trt * TR;
    const float* kbase = keys + ((size_t)batch * S_ + row0) * D_;

    float acc[TR][8];
#pragma unroll
    for (int i = 0; i < TR; ++i)
#pragma unroll
        for (int j = 0; j < 8; ++j) acc[i][j] = 0.f;

    for (int d0 = 0; d0 < D_; d0 += 4) {
        float4 k[TR];
#pragma unroll
        for (int i = 0; i < TR; ++i)
            k[i] = *(const float4*)(kbase + (size_t)i * D_ + d0);
#pragma unroll
        for (int dd = 0; dd < 4; ++dd) {
            const float4 c0 = *(const float4*)&cnT[(d0 + dd) * C_ + tc * 8];
            const float4 c1 = *(const float4*)&cnT[(d0 + dd) * C_ + tc * 8 + 4];
            const float cw[8] = {c0.x, c0.y, c0.z, c0.w, c1.x, c1.y, c1.z, c1.w};
#pragma unroll
            for (int i = 0; i < TR; ++i) {
                const float kv = dd == 0 ? k[i].x : dd == 1 ? k[i].y
                               : dd == 2 ? k[i].z : k[i].w;
#pragma unroll
                for (int j = 0; j < 8; ++j)
                    acc[i][j] = fmaf(kv, cw[j], acc[i][j]);
            }
        }
    }

    // argmax per row across the 8 tc lanes; first-max-index tie-break (jnp.argmax)
    const float* mrow = mask + (size_t)batch * S_ + row0;
#pragma unroll
    for (int i = 0; i < TR; ++i) {
        float bv = acc[i][0];
        int bi = tc * 8;
#pragma unroll
        for (int j = 1; j < 8; ++j)
            if (acc[i][j] > bv) { bv = acc[i][j]; bi = tc * 8 + j; }
#pragma unroll
        for (int m = 1; m < 8; m <<= 1) {
            float ov = __shfl_xor(bv, m, 8);
            int   oi = __shfl_xor(bi, m, 8);
            if (ov > bv || (ov == bv && oi < bi)) { bv = ov; bi = oi; }
        }
        if (tc == 0) {
            float mv = mrow[i];
            int a = (mv != 0.f) ? bi : C_;     // C_ == sentinel: skip accumulation
            asgL[trt * TR + i] = (short)a;
            out_asg[(size_t)batch * S_ + row0 + i] = (float)((mv != 0.f) ? bi : 0);
            if (mv != 0.f) atomicAdd(&cntL[bi], 1.f);
        }
    }
    __syncthreads();

    // accumulate keys/values into LDS accumulators (2 rows per iteration)
    {
        const float* kb = keys + ((size_t)batch * S_ + srow0) * D_;
        const float* vb = values + ((size_t)batch * S_ + srow0) * D_;
        const int half = tid >> 8;   // 0 or 1
        const int t = tid & 255;
        for (int rr = 0; rr < ROWS_PB; rr += 2) {
            int row = rr + half;
            int a = asgL[row];
            if (a < C_) {
                if (t < 128)
                    atomicAdd(&accK[a * D_ + t], kb[(size_t)row * D_ + t]);
                else
                    atomicAdd(&accV[a * D_ + (t - 128)], vb[(size_t)row * D_ + (t - 128)]);
            }
        }
    }
    __syncthreads();

    // flush block partials to global
    {
        float* gks = g_ksum + (size_t)batch * C_ * D_;
        float* gvs = g_vsum + (size_t)batch * C_ * D_;
        for (int i = tid; i < C_ * D_; i += THREADS) {
            atomicAdd(&gks[i], accK[i]);
            atomicAdd(&gvs[i], accV[i]);
        }
        if (tid < C_) atomicAdd(&g_cnt[batch * C_ + tid], cntL[tid]);
    }
}

__global__ void finalize_k(const float* __restrict__ ws,
                           const float* __restrict__ cen,
                           float* __restrict__ out) {
    int idx = blockIdx.x * blockDim.x + threadIdx.x;   // < B*C*D
    const float* ksum = ws + WS_KSUM_OFF;
    const float* vsum = ws + WS_VSUM_OFF;
    const float* cnt  = ws + WS_CNTS_OFF;
    int bc = idx >> 7;             // b*64 + c
    int cd = idx & (C_ * D_ - 1);  // c*128 + d
    float n = cnt[bc];
    float cc, cv;
    if (n > 0.f) {
        cc = ksum[idx] / n;
        cv = vsum[idx] / n;
    } else {
        cc = cen[cd];
        cv = 0.f;
    }
    out[idx] = cc;
    out[B_ * C_ * D_ + idx] = cv;
}

extern "C" void kernel_launch(void* const* d_in, const int* in_sizes, int n_in,
                              void* d_out, int out_size, void* d_ws, size_t ws_size,
                              hipStream_t stream) {
    const float* keys   = (const float*)d_in[0];
    const float* values = (const float*)d_in[1];
    const float* mask   = (const float*)d_in[2];
    const float* cen    = (const float*)d_in[3];
    float* ws  = (float*)d_ws;
    float* out = (float*)d_out;

    // zero the accumulator region (ksum, vsum, counts) every call
    hipMemsetAsync(ws + WS_KSUM_OFF, 0,
                   (size_t)(2 * B_ * C_ * D_ + B_ * C_) * sizeof(float), stream);

    normalize_centroids_k<<<1, 512, 0, stream>>>(cen, ws + WS_CNT_OFF);

    assign_accum_k<<<256, THREADS, 0, stream>>>(
        keys, values, mask, ws + WS_CNT_OFF,
        ws + WS_KSUM_OFF, ws + WS_VSUM_OFF, ws + WS_CNTS_OFF,
        out + 2 * B_ * C_ * D_);

    finalize_k<<<(B_ * C_ * D_) / 256, 256, 0, stream>>>(ws, cen, out);
}